// Round 1
// baseline (2106.888 us; speedup 1.0000x reference)
//
#include <hip/hip_runtime.h>
#include <math.h>

// Problem constants (from reference)
#define Bn     32768
#define Ln     35
#define CINn   21
#define Fn     128
#define Kn     9
#define Hn     64
#define NFLANK 10
#define CFLANK 10

// LDS layout (float indices)
#define CONV_STRIDE 132                 // 128 + 4 pad: breaks 4-way bank conflict on column reads
#define S_CONV   0                      // 35*132 = 4620
#define REGION2  4620                   // 8192-float union region
#define S_SEQ    REGION2                // phase A: 48*21 = 1008 (zero-padded seq)
#define SEQ_ROWS 48
#define S_WK     (REGION2 + 1008)       // phase A: 21*128 = 2688 (one k-slice of conv_w)
#define S_W1     REGION2                // phase B: 128*64 = 8192 (n_w1 / c_w1)
#define S_Y      (REGION2 + 8192)       // yn[40], yc[40]
#define S_MISC   (S_Y + 80)             // avg_n, avg_c
#define SMEM_FLOATS (S_MISC + 2)        // 12894 floats = 51.6 KB -> ~3 blocks/CU

__global__ __launch_bounds__(256) void fused_kernel(
    const float* __restrict__ seq,    const int*   __restrict__ plen_arr,
    const float* __restrict__ conv_w, const float* __restrict__ conv_b,
    const float* __restrict__ n_w1,   const float* __restrict__ n_b1,
    const float* __restrict__ n_w2,   const float* __restrict__ n_b2,
    const float* __restrict__ c_w1,   const float* __restrict__ c_b1,
    const float* __restrict__ c_w2,   const float* __restrict__ c_b2,
    const float* __restrict__ navg_w, const float* __restrict__ navg_b,
    const float* __restrict__ cavg_w, const float* __restrict__ cavg_b,
    const float* __restrict__ out_w,  const float* __restrict__ out_b,
    float* __restrict__ out)
{
    __shared__ float sm[SMEM_FLOATS];
    const int t = threadIdx.x;
    const int b = blockIdx.x;
    const int plen = plen_arr[b];

    // ---- stage zero-padded sequence row: rows [0,4) and [39,48) are zero pad ----
    // left pad: 4*21 = 84 floats; right pad: (48-39)*21 = 189 floats. No overlap with data.
    if (t < 4 * CINn)   sm[S_SEQ + t] = 0.0f;
    if (t < 9 * CINn)   sm[S_SEQ + (4 + Ln) * CINn + t] = 0.0f;
    for (int idx = t; idx < Ln * CINn; idx += 256)
        sm[S_SEQ + 4 * CINn + idx] = seq[(size_t)b * (Ln * CINn) + idx];

    // ---- conv phase: thread owns f4 = 4 channels x 5 l-positions (stride 8) ----
    const int tf = t & 31, tl = t >> 5;
    const int f4 = tf * 4;
    float acc[5][4];
    {
        float4 cb = *(const float4*)(conv_b + f4);
        #pragma unroll
        for (int i = 0; i < 5; i++) { acc[i][0]=cb.x; acc[i][1]=cb.y; acc[i][2]=cb.z; acc[i][3]=cb.w; }
    }

    for (int k = 0; k < Kn; k++) {
        __syncthreads();                               // protect s_wk reuse (and cover seq stores, k=0)
        for (int idx = t; idx < CINn * Fn; idx += 256)
            sm[S_WK + idx] = conv_w[k * CINn * Fn + idx];
        __syncthreads();
        #pragma unroll
        for (int c = 0; c < CINn; c++) {
            float4 w4 = *(const float4*)&sm[S_WK + c * Fn + f4];
            #pragma unroll
            for (int i = 0; i < 5; i++) {
                float sv = sm[S_SEQ + (tl + 8 * i + k) * CINn + c];  // zero-padded -> no branch
                acc[i][0] += sv * w4.x; acc[i][1] += sv * w4.y;
                acc[i][2] += sv * w4.z; acc[i][3] += sv * w4.w;
            }
        }
    }
    // relu + store conv_result to LDS
    #pragma unroll
    for (int i = 0; i < 5; i++) {
        int l = tl + 8 * i;
        if (l < Ln) {
            float4 v;
            v.x = fmaxf(acc[i][0], 0.f); v.y = fmaxf(acc[i][1], 0.f);
            v.z = fmaxf(acc[i][2], 0.f); v.w = fmaxf(acc[i][3], 0.f);
            *(float4*)&sm[S_CONV + l * CONV_STRIDE + f4] = v;
        }
    }

    // ---- post MLPs (n then c): h = relu(conv @ w1 + b1); y = tanh(h @ w2 + b2) ----
    const int tj = t & 15, j4 = tj * 4, tl2 = t >> 4;
    int lidx[3]; bool lval[3];
    #pragma unroll
    for (int i = 0; i < 3; i++) {
        int l = tl2 + 16 * i;
        lval[i] = (l < Ln);
        lidx[i] = lval[i] ? l : (Ln - 1);              // clamp so LDS reads stay in-bounds
    }

    for (int which = 0; which < 2; which++) {
        const float* w1 = which ? c_w1 : n_w1;
        const float* b1 = which ? c_b1 : n_b1;
        const float* w2 = which ? c_w2 : n_w2;
        const float* b2 = which ? c_b2 : n_b2;

        __syncthreads();                               // covers s_conv stores (iter 0) / s_w1 reuse (iter 1)
        for (int idx = t; idx < Fn * Hn; idx += 256)
            sm[S_W1 + idx] = w1[idx];
        __syncthreads();

        float a2[3][4];
        {
            float4 bb = *(const float4*)(b1 + j4);
            #pragma unroll
            for (int i = 0; i < 3; i++) { a2[i][0]=bb.x; a2[i][1]=bb.y; a2[i][2]=bb.z; a2[i][3]=bb.w; }
        }

        for (int fb = 0; fb < Fn / 4; fb++) {
            float4 cv0 = *(const float4*)&sm[S_CONV + lidx[0] * CONV_STRIDE + fb * 4];
            float4 cv1 = *(const float4*)&sm[S_CONV + lidx[1] * CONV_STRIDE + fb * 4];
            float4 cv2 = *(const float4*)&sm[S_CONV + lidx[2] * CONV_STRIDE + fb * 4];
            const float* cp0 = (const float*)&cv0;
            const float* cp1 = (const float*)&cv1;
            const float* cp2 = (const float*)&cv2;
            #pragma unroll
            for (int r = 0; r < 4; r++) {
                float4 w4 = *(const float4*)&sm[S_W1 + (fb * 4 + r) * Hn + j4];
                a2[0][0] += cp0[r] * w4.x; a2[0][1] += cp0[r] * w4.y; a2[0][2] += cp0[r] * w4.z; a2[0][3] += cp0[r] * w4.w;
                a2[1][0] += cp1[r] * w4.x; a2[1][1] += cp1[r] * w4.y; a2[1][2] += cp1[r] * w4.z; a2[1][3] += cp1[r] * w4.w;
                a2[2][0] += cp2[r] * w4.x; a2[2][1] += cp2[r] * w4.y; a2[2][2] += cp2[r] * w4.z; a2[2][3] += cp2[r] * w4.w;
            }
        }

        float4 w2v = *(const float4*)(w2 + j4);
        float bb2 = b2[0];
        #pragma unroll
        for (int i = 0; i < 3; i++) {
            float p = fmaxf(a2[i][0], 0.f) * w2v.x + fmaxf(a2[i][1], 0.f) * w2v.y
                    + fmaxf(a2[i][2], 0.f) * w2v.z + fmaxf(a2[i][3], 0.f) * w2v.w;
            // reduce across the 16 lanes of this tj-group (all share the same l)
            p += __shfl_xor(p, 8); p += __shfl_xor(p, 4);
            p += __shfl_xor(p, 2); p += __shfl_xor(p, 1);
            if (tj == 0 && lval[i])
                sm[S_Y + which * 40 + (tl2 + 16 * i)] = tanhf(p + bb2);
        }
    }

    // ---- flank averages: wave0 -> avg_n, wave1 -> avg_c ----
    __syncthreads();
    const int wv = t >> 6, ln = t & 63;
    if (wv == 0) {
        float p = 0.f;
        #pragma unroll
        for (int h = 0; h < 2; h++) {
            int f = ln + 64 * h;
            float s = 0.f;
            for (int l = 0; l < NFLANK; l++) s += sm[S_CONV + l * CONV_STRIDE + f];
            p += (s * (1.0f / NFLANK)) * navg_w[f];
        }
        p += __shfl_xor(p, 32); p += __shfl_xor(p, 16); p += __shfl_xor(p, 8);
        p += __shfl_xor(p, 4);  p += __shfl_xor(p, 2);  p += __shfl_xor(p, 1);
        if (ln == 0) sm[S_MISC + 0] = tanhf(p + navg_b[0]);
    } else if (wv == 1) {
        // window [10+plen, 10+plen+10): always fully inside [0,35); cnt==10,
        // and (sum(conv+1)/10 - 1) == mean(conv) over the window.
        int start = NFLANK + plen;
        float p = 0.f;
        #pragma unroll
        for (int h = 0; h < 2; h++) {
            int f = ln + 64 * h;
            float s = 0.f;
            for (int l = 0; l < CFLANK; l++) s += sm[S_CONV + (start + l) * CONV_STRIDE + f];
            p += (s * (1.0f / CFLANK)) * cavg_w[f];
        }
        p += __shfl_xor(p, 32); p += __shfl_xor(p, 16); p += __shfl_xor(p, 8);
        p += __shfl_xor(p, 4);  p += __shfl_xor(p, 2);  p += __shfl_xor(p, 1);
        if (ln == 0) sm[S_MISC + 1] = tanhf(p + cavg_b[0]);
    }
    __syncthreads();

    // ---- final combine (thread 0) ----
    if (t == 0) {
        float cleaved_n = sm[S_Y + NFLANK];
        float mn = 0.f;   // reference maxes (y+1)*mask over ALL l, unmasked contribute 0
        for (int l = NFLANK + 1; l < NFLANK + plen; l++) mn = fmaxf(mn, sm[S_Y + l] + 1.f);
        float maxpool_n = -(mn - 1.f);
        float cleaved_c = sm[S_Y + 40 + NFLANK + plen - 1];
        float mc = 0.f;
        for (int l = NFLANK; l < NFLANK + plen - 1; l++) mc = fmaxf(mc, sm[S_Y + 40 + l] + 1.f);
        float maxpool_c = -(mc - 1.f);
        float comb = cleaved_n * out_w[0] + maxpool_n * out_w[1] + sm[S_MISC + 0] * out_w[2]
                   + cleaved_c * out_w[3] + maxpool_c * out_w[4] + sm[S_MISC + 1] * out_w[5]
                   + out_b[0];
        out[b] = 1.f / (1.f + expf(-comb));
    }
}

extern "C" void kernel_launch(void* const* d_in, const int* in_sizes, int n_in,
                              void* d_out, int out_size, void* d_ws, size_t ws_size,
                              hipStream_t stream) {
    const int batches = in_sizes[1];   // peptide_length count == B
    fused_kernel<<<batches, 256, 0, stream>>>(
        (const float*)d_in[0],  (const int*)d_in[1],
        (const float*)d_in[2],  (const float*)d_in[3],
        (const float*)d_in[4],  (const float*)d_in[5],
        (const float*)d_in[6],  (const float*)d_in[7],
        (const float*)d_in[8],  (const float*)d_in[9],
        (const float*)d_in[10], (const float*)d_in[11],
        (const float*)d_in[12], (const float*)d_in[13],
        (const float*)d_in[14], (const float*)d_in[15],
        (const float*)d_in[16], (const float*)d_in[17],
        (float*)d_out);
}

// Round 3
// 438.589 us; speedup vs baseline: 4.8038x; 4.8038x over previous
//
#include <hip/hip_runtime.h>
#include <hip/hip_bf16.h>
#include <math.h>

// Problem constants
#define Ln     35
#define CINn   21
#define CINP   24      // padded CIN (multiple of 8 -> aligned b128 im2col reads)
#define Fn     128
#define Kn     9
#define Hn     64
#define GB     16      // batch rows per block
#define SEQ_STRIDE 1160  // 48*24=1152 +8 pad (keeps 16B align; 2-way bank alias is free)
#define TILE_STRIDE 136  // 128 + 8 pad

typedef __attribute__((ext_vector_type(8))) short short8;
typedef __attribute__((ext_vector_type(4))) float f32x4;

static __device__ __forceinline__ short bf16bits(float f) {
    __hip_bfloat16 h = __float2bfloat16(f);
    return *(short*)&h;
}

// ---------------- single fused kernel: 16 batch rows / block, no workspace ----------------
__global__ __launch_bounds__(256, 2) void fused_kernel(
    const float* __restrict__ seq,    const int*   __restrict__ plen_arr,
    const float* __restrict__ conv_w, const float* __restrict__ conv_b,
    const float* __restrict__ n_w1,   const float* __restrict__ n_b1,
    const float* __restrict__ n_w2,   const float* __restrict__ n_b2,
    const float* __restrict__ c_w1,   const float* __restrict__ c_b1,
    const float* __restrict__ c_w2,   const float* __restrict__ c_b2,
    const float* __restrict__ navg_w, const float* __restrict__ navg_b,
    const float* __restrict__ cavg_w, const float* __restrict__ cavg_b,
    const float* __restrict__ out_w,  const float* __restrict__ out_b,
    float* __restrict__ out)
{
    __shared__ __align__(16) unsigned short s_seq[GB * SEQ_STRIDE];      // 37120 B
    __shared__ __align__(16) unsigned short s_tile[2][GB * TILE_STRIDE]; // 8704 B
    __shared__ __align__(16) float s_yp[Ln][4][GB];                      // 8960 B
    __shared__ __align__(16) float s_avg[2][4][GB];                      // 512 B
    __shared__ __align__(16) float s_y[2][GB][36];                       // 4608 B

    const int t    = threadIdx.x;
    const int wave = t >> 6;
    const int lane = t & 63;
    const int quad = lane >> 4;
    const int col  = lane & 15;
    const int b0   = blockIdx.x * GB;

    // ---- zero-init padded seq (pad rows + pad channels must be 0) ----
    {
        uint4* p = (uint4*)s_seq;                    // 37120/16 = 2320 uint4
        for (int i = t; i < (GB * SEQ_STRIDE) / 8; i += 256)
            p[i] = make_uint4(0u, 0u, 0u, 0u);
    }

    // ---- per-lane loop-invariant weight fragments, gathered in-kernel ----
    // conv B-frag: B[kk=32s+quad*8+j][n=ng], kk' = k*24+c, zero for c>=21 / k>=9
    // MLP  B-frag: B[k =32s+quad*8+j][n=ng], n<64 -> n_w1, n>=64 -> c_w1
    short8 wb[2][7];
    short8 w1b[2][4];
    float  cbias[2], b1v[2], w2v[2], navw[2], cavw[2];
    const int head = wave >> 1;            // 0 = n-head (waves 0,1), 1 = c (waves 2,3)
    #pragma unroll
    for (int tt = 0; tt < 2; tt++) {
        const int ng = (2 * wave + tt) * 16 + col;   // 0..127 (conv f AND mlp n index)
        #pragma unroll
        for (int s = 0; s < 7; s++) {
            short8 v;
            #pragma unroll
            for (int j = 0; j < 8; j++) {
                int kk = 32 * s + quad * 8 + j;
                int k = kk / CINP, c = kk % CINP;
                float f = (k < Kn && c < CINn) ? conv_w[(k * CINn + c) * Fn + ng] : 0.0f;
                v[j] = bf16bits(f);
            }
            wb[tt][s] = v;
        }
        const int nl = ng & 63;
        #pragma unroll
        for (int s = 0; s < 4; s++) {
            short8 v;
            #pragma unroll
            for (int j = 0; j < 8; j++) {
                int k = 32 * s + quad * 8 + j;
                float f = head ? c_w1[k * Hn + nl] : n_w1[k * Hn + nl];
                v[j] = bf16bits(f);
            }
            w1b[tt][s] = v;
        }
        cbias[tt] = conv_b[ng];
        navw[tt]  = navg_w[ng];
        cavw[tt]  = cavg_w[ng];
        b1v[tt] = head ? c_b1[nl] : n_b1[nl];
        w2v[tt] = head ? c_w2[nl] : n_w2[nl];
    }
    int plen_r[4];
    #pragma unroll
    for (int r = 0; r < 4; r++) plen_r[r] = plen_arr[b0 + quad * 4 + r];

    __syncthreads();   // zero-init done before data fill (regions overlap)

    // ---- stage seq -> bf16 LDS, rows shifted +4 (SAME pad), c<21 only ----
    for (int i = t; i < GB * Ln * CINn; i += 256) {
        int bi = i / (Ln * CINn), r = i % (Ln * CINn);
        int l = r / CINn, c = r % CINn;
        s_seq[bi * SEQ_STRIDE + (4 + l) * CINP + c] =
            (unsigned short)bf16bits(seq[(size_t)(b0 + bi) * (Ln * CINn) + r]);
    }
    __syncthreads();

    float sum_n[2][4] = {{0.f,0.f,0.f,0.f},{0.f,0.f,0.f,0.f}};
    float sum_c[2][4] = {{0.f,0.f,0.f,0.f},{0.f,0.f,0.f,0.f}};

    for (int l = 0; l < Ln; l++) {
        // ---- conv GEMM: D[m=batch][n=f], A = im2col window (contiguous in padded seq) ----
        short8 af[7];
        #pragma unroll
        for (int s = 0; s < 7; s++)
            af[s] = *(const short8*)&s_seq[col * SEQ_STRIDE + l * CINP + 32 * s + quad * 8];
        f32x4 cacc[2] = {{0.f,0.f,0.f,0.f},{0.f,0.f,0.f,0.f}};
        #pragma unroll
        for (int s = 0; s < 7; s++) {
            cacc[0] = __builtin_amdgcn_mfma_f32_16x16x32_bf16(af[s], wb[0][s], cacc[0], 0, 0, 0);
            cacc[1] = __builtin_amdgcn_mfma_f32_16x16x32_bf16(af[s], wb[1][s], cacc[1], 0, 0, 0);
        }
        const int buf = l & 1;
        #pragma unroll
        for (int tt = 0; tt < 2; tt++) {
            #pragma unroll
            for (int r = 0; r < 4; r++) {
                float v = fmaxf(cacc[tt][r] + cbias[tt], 0.0f);   // relu(conv)
                sum_n[tt][r] += (l < 10) ? v : 0.0f;
                bool inc = (l >= 10 + plen_r[r]) && (l < 20 + plen_r[r]);
                sum_c[tt][r] += inc ? v : 0.0f;
                s_tile[buf][(quad * 4 + r) * TILE_STRIDE + (2 * wave + tt) * 16 + col] =
                    (unsigned short)bf16bits(v);
            }
        }
        __syncthreads();   // conv tile written -> MLP may read

        // ---- MLP layer1 GEMM: D[m][n=h-dim(2 heads)], K = 128 f ----
        short8 am[4];
        #pragma unroll
        for (int s = 0; s < 4; s++)
            am[s] = *(const short8*)&s_tile[buf][col * TILE_STRIDE + 32 * s + quad * 8];
        f32x4 hacc[2] = {{0.f,0.f,0.f,0.f},{0.f,0.f,0.f,0.f}};
        #pragma unroll
        for (int s = 0; s < 4; s++) {
            hacc[0] = __builtin_amdgcn_mfma_f32_16x16x32_bf16(am[s], w1b[0][s], hacc[0], 0, 0, 0);
            hacc[1] = __builtin_amdgcn_mfma_f32_16x16x32_bf16(am[s], w1b[1][s], hacc[1], 0, 0, 0);
        }
        // ---- y = relu(h+b1) @ w2 : per-lane partial, reduce over 16 cols ----
        float p[4];
        #pragma unroll
        for (int r = 0; r < 4; r++)
            p[r] = fmaxf(hacc[0][r] + b1v[0], 0.f) * w2v[0]
                 + fmaxf(hacc[1][r] + b1v[1], 0.f) * w2v[1];
        #pragma unroll
        for (int r = 0; r < 4; r++) {
            p[r] += __shfl_xor(p[r], 1);
            p[r] += __shfl_xor(p[r], 2);
            p[r] += __shfl_xor(p[r], 4);
            p[r] += __shfl_xor(p[r], 8);
        }
        if (col == 0)
            *(f32x4*)&s_yp[l][wave][quad * 4] = (f32x4){p[0], p[1], p[2], p[3]};
        // no barrier: next iter writes s_tile[buf^1]; the write-after-read hazard on
        // s_tile[buf] (iter l+2) is fenced by iter l+1's __syncthreads.
    }

    // ---- flank-average partials: reduce register sums over 16 cols ----
    {
        float an[4], ac[4];
        #pragma unroll
        for (int r = 0; r < 4; r++) {
            an[r] = sum_n[0][r] * navw[0] + sum_n[1][r] * navw[1];
            ac[r] = sum_c[0][r] * cavw[0] + sum_c[1][r] * cavw[1];
        }
        #pragma unroll
        for (int r = 0; r < 4; r++) {
            an[r] += __shfl_xor(an[r], 1); an[r] += __shfl_xor(an[r], 2);
            an[r] += __shfl_xor(an[r], 4); an[r] += __shfl_xor(an[r], 8);
            ac[r] += __shfl_xor(ac[r], 1); ac[r] += __shfl_xor(ac[r], 2);
            ac[r] += __shfl_xor(ac[r], 4); ac[r] += __shfl_xor(ac[r], 8);
        }
        if (col == 0) {
            *(f32x4*)&s_avg[0][wave][quad * 4] = (f32x4){an[0], an[1], an[2], an[3]};
            *(f32x4*)&s_avg[1][wave][quad * 4] = (f32x4){ac[0], ac[1], ac[2], ac[3]};
        }
    }
    __syncthreads();

    // ---- y finalize: y = tanh(partial_w0 + partial_w1 + b2), 1120 values ----
    {
        const float bn = n_b2[0], bc = c_b2[0];
        for (int i = t; i < 2 * GB * Ln; i += 256) {
            int hd = i / (GB * Ln), rem = i % (GB * Ln);
            int m = rem / Ln, l = rem % Ln;
            float v = s_yp[l][hd * 2][m] + s_yp[l][hd * 2 + 1][m] + (hd ? bc : bn);
            s_y[hd][m][l] = tanhf(v);
        }
    }
    __syncthreads();

    // ---- final combine: one thread per batch row ----
    if (t < GB) {
        const int m = t;
        const int plen = plen_arr[b0 + m];
        float cleaved_n = s_y[0][m][10];
        float mn = 0.f;   // reference maxes (y+1)*mask over ALL l, unmasked contribute 0
        for (int l = 11; l < 10 + plen; l++) mn = fmaxf(mn, s_y[0][m][l] + 1.f);
        float maxpool_n = -(mn - 1.f);
        float cleaved_c = s_y[1][m][10 + plen - 1];
        float mc = 0.f;
        for (int l = 10; l < 10 + plen - 1; l++) mc = fmaxf(mc, s_y[1][m][l] + 1.f);
        float maxpool_c = -(mc - 1.f);
        float avg_n = tanhf((s_avg[0][0][m] + s_avg[0][1][m] + s_avg[0][2][m] + s_avg[0][3][m])
                            * 0.1f + navg_b[0]);
        float avg_c = tanhf((s_avg[1][0][m] + s_avg[1][1][m] + s_avg[1][2][m] + s_avg[1][3][m])
                            * 0.1f + cavg_b[0]);
        float comb = cleaved_n * out_w[0] + maxpool_n * out_w[1] + avg_n * out_w[2]
                   + cleaved_c * out_w[3] + maxpool_c * out_w[4] + avg_c * out_w[5]
                   + out_b[0];
        out[b0 + m] = 1.f / (1.f + expf(-comb));
    }
}

extern "C" void kernel_launch(void* const* d_in, const int* in_sizes, int n_in,
                              void* d_out, int out_size, void* d_ws, size_t ws_size,
                              hipStream_t stream) {
    const int B = in_sizes[1];
    fused_kernel<<<B / GB, 256, 0, stream>>>(
        (const float*)d_in[0],  (const int*)d_in[1],
        (const float*)d_in[2],  (const float*)d_in[3],
        (const float*)d_in[4],  (const float*)d_in[5],
        (const float*)d_in[6],  (const float*)d_in[7],
        (const float*)d_in[8],  (const float*)d_in[9],
        (const float*)d_in[10], (const float*)d_in[11],
        (const float*)d_in[12], (const float*)d_in[13],
        (const float*)d_in[14], (const float*)d_in[15],
        (const float*)d_in[16], (const float*)d_in[17],
        (float*)d_out);
}